// Round 6
// baseline (240.046 us; speedup 1.0000x reference)
//
#include <hip/hip_runtime.h>
#include <cstdint>
#include <cstddef>

#define GG 512
#define NF 64
#define EPSF 1e-5f

__device__ __forceinline__ void atomAddF(float* p, float v) {
    unsafeAtomicAdd(p, v);   // hardware global_atomic_add_f32
}

// ---------------- Pass A: per-graph sum / sumsq / count of x00 ----------------
__global__ __launch_bounds__(256) void k_stats(const float* __restrict__ x00, const int* __restrict__ gid,
                        float* __restrict__ gsum, float* __restrict__ gsq,
                        float* __restrict__ gcnt, int N)
{
    int w = (blockIdx.x * blockDim.x + threadIdx.x) >> 6;
    int lane = threadIdx.x & 63;
    long base = (long)w * 64;
    int gf = gid[base];
    int gl = gid[base + 63];
    if (gf == gl) {
        const float4* p = reinterpret_cast<const float4*>(x00 + base * NF) + lane;
        float s0=0,s1=0,s2=0,s3=0,q0=0,q1=0,q2=0,q3=0;
        #pragma unroll
        for (int k = 0; k < 16; ++k) {
            float4 v = p[k * 64];
            s0+=v.x; s1+=v.y; s2+=v.z; s3+=v.w;
            q0=fmaf(v.x,v.x,q0); q1=fmaf(v.y,v.y,q1); q2=fmaf(v.z,v.z,q2); q3=fmaf(v.w,v.w,q3);
        }
        #pragma unroll
        for (int m = 16; m < 64; m <<= 1) {
            s0+=__shfl_xor(s0,m); s1+=__shfl_xor(s1,m); s2+=__shfl_xor(s2,m); s3+=__shfl_xor(s3,m);
            q0+=__shfl_xor(q0,m); q1+=__shfl_xor(q1,m); q2+=__shfl_xor(q2,m); q3+=__shfl_xor(q3,m);
        }
        if (lane < 16) {
            float* ds = gsum + gf * NF + lane * 4;
            float* dq = gsq  + gf * NF + lane * 4;
            atomAddF(ds+0,s0); atomAddF(ds+1,s1); atomAddF(ds+2,s2); atomAddF(ds+3,s3);
            atomAddF(dq+0,q0); atomAddF(dq+1,q1); atomAddF(dq+2,q2); atomAddF(dq+3,q3);
        }
        if (lane == 0) atomAddF(&gcnt[gf], 64.0f);
    } else {
        int myg = gid[base + lane];
        int cur = gf;
        float s = 0.f, q = 0.f, cnt = 0.f;
        for (int k = 0; k < 64; ++k) {
            int g = __shfl(myg, k);
            if (g != cur) {
                atomAddF(&gsum[cur * NF + lane], s);
                atomAddF(&gsq [cur * NF + lane], q);
                if (lane == 0) atomAddF(&gcnt[cur], cnt);
                s = q = cnt = 0.f; cur = g;
            }
            float v = x00[(base + k) * NF + lane];
            s += v; q = fmaf(v, v, q); cnt += 1.f;
        }
        atomAddF(&gsum[cur * NF + lane], s);
        atomAddF(&gsq [cur * NF + lane], q);
        if (lane == 0) atomAddF(&gcnt[cur], cnt);
    }
}

// ------------- Per-graph effective affine weights for logits ------------------
__global__ void k_prep(const float* __restrict__ gsum, const float* __restrict__ gsq,
                       const float* __restrict__ gcnt,
                       const float* __restrict__ gamma, const float* __restrict__ beta,
                       const float* __restrict__ lin_w, const float* __restrict__ lin_b,
                       float* __restrict__ Aeff, float* __restrict__ Beff)
{
    int g = blockIdx.x;
    int c = threadIdx.x;           // 64 threads = 1 wave
    float cnt = fmaxf(gcnt[g], 1.f);
    float mean = gsum[g * NF + c] / cnt;
    float var  = gsq [g * NF + c] / cnt - mean * mean;
    float rs = rsqrtf(var + EPSF);
    float ga = gamma[c], be = beta[c];
    #pragma unroll
    for (int j = 0; j < 3; ++j) {
        float wv = lin_w[j * NF + c];
        Aeff[((long)g * 3 + j) * NF + c] = rs * ga * wv;
        float term = (be - mean * rs * ga) * wv;
        #pragma unroll
        for (int m = 32; m; m >>= 1) term += __shfl_xor(term, m);
        if (c == 0) Beff[g * 3 + j] = term + lin_b[j];
    }
}

// --------- Pass B: logits -> e (no max-shift), pos-weighted sums, e-sums ------
__global__ __launch_bounds__(128) void k_logits(const float* __restrict__ x00, const int* __restrict__ gid,
                         const float* __restrict__ pos,
                         const float* __restrict__ Aeff, const float* __restrict__ Beff,
                         float* __restrict__ ebp, float* __restrict__ accum, int N)
{
    __shared__ float T2[2][64 * 68];
    int wid = threadIdx.x >> 6;
    int lane = threadIdx.x & 63;
    long chunk = (long)blockIdx.x * 2 + wid;
    long base = chunk * 64;
    float* T = T2[wid];

    const float* src = x00 + base * NF;
    #pragma unroll
    for (int k = 0; k < 16; ++k) {
        int fl = k * 256 + lane * 4;
        float4 v = *reinterpret_cast<const float4*>(src + fl);
        int n = fl >> 6, c = fl & 63;
        *reinterpret_cast<float4*>(&T[n * 68 + c]) = v;
    }
    __syncthreads();

    int gf = gid[base], gl = gid[base + 63];
    float l0, l1, l2;
    int g_l;
    if (gf == gl) {
        g_l = gf;
        const float* ap = Aeff + (size_t)gf * 192;
        float a0a=0,a0b=0,a1a=0,a1b=0,a2a=0,a2b=0;
        #pragma unroll
        for (int t = 0; t < 16; ++t) {
            float4 xv = *reinterpret_cast<const float4*>(&T[lane * 68 + 4 * t]);
            float4 w0 = *reinterpret_cast<const float4*>(ap + 4 * t);
            float4 w1 = *reinterpret_cast<const float4*>(ap + 64 + 4 * t);
            float4 w2 = *reinterpret_cast<const float4*>(ap + 128 + 4 * t);
            a0a = fmaf(xv.x,w0.x,fmaf(xv.y,w0.y,a0a)); a0b = fmaf(xv.z,w0.z,fmaf(xv.w,w0.w,a0b));
            a1a = fmaf(xv.x,w1.x,fmaf(xv.y,w1.y,a1a)); a1b = fmaf(xv.z,w1.z,fmaf(xv.w,w1.w,a1b));
            a2a = fmaf(xv.x,w2.x,fmaf(xv.y,w2.y,a2a)); a2b = fmaf(xv.z,w2.z,fmaf(xv.w,w2.w,a2b));
        }
        l0 = a0a + a0b + Beff[gf*3+0];
        l1 = a1a + a1b + Beff[gf*3+1];
        l2 = a2a + a2b + Beff[gf*3+2];
    } else {
        g_l = gid[base + lane];
        const float* ap = Aeff + (size_t)g_l * 192;
        float a0=0,a1=0,a2=0;
        #pragma unroll
        for (int t = 0; t < 16; ++t) {
            float4 xv = *reinterpret_cast<const float4*>(&T[lane * 68 + 4 * t]);
            float4 w0 = *reinterpret_cast<const float4*>(ap + 4 * t);
            float4 w1 = *reinterpret_cast<const float4*>(ap + 64 + 4 * t);
            float4 w2 = *reinterpret_cast<const float4*>(ap + 128 + 4 * t);
            a0 = fmaf(xv.x,w0.x,fmaf(xv.y,w0.y,fmaf(xv.z,w0.z,fmaf(xv.w,w0.w,a0))));
            a1 = fmaf(xv.x,w1.x,fmaf(xv.y,w1.y,fmaf(xv.z,w1.z,fmaf(xv.w,w1.w,a1))));
            a2 = fmaf(xv.x,w2.x,fmaf(xv.y,w2.y,fmaf(xv.z,w2.z,fmaf(xv.w,w2.w,a2))));
        }
        l0 = a0 + Beff[g_l*3+0];
        l1 = a1 + Beff[g_l*3+1];
        l2 = a2 + Beff[g_l*3+2];
    }
    float e0 = expf(l0), e1 = expf(l1), e2 = expf(l2);
    long node = base + lane;
    ebp[node]            = e0;
    ebp[(long)N + node]  = e1;
    ebp[2L * N + node]   = e2;

    const float* pp = pos + node * 6;
    float2 v01 = *reinterpret_cast<const float2*>(pp);
    float2 v23 = *reinterpret_cast<const float2*>(pp + 2);
    float2 v45 = *reinterpret_cast<const float2*>(pp + 4);
    float p0 = v01.x*e2, p1 = v01.y*e2, p2 = v23.x*e2, p3 = v23.y*e2, p4 = v45.x*e2, p5 = v45.y*e2;
    if (gf == gl) {
        #pragma unroll
        for (int m = 1; m < 64; m <<= 1) {
            e0+=__shfl_xor(e0,m); e1+=__shfl_xor(e1,m); e2+=__shfl_xor(e2,m);
            p0+=__shfl_xor(p0,m); p1+=__shfl_xor(p1,m); p2+=__shfl_xor(p2,m);
            p3+=__shfl_xor(p3,m); p4+=__shfl_xor(p4,m); p5+=__shfl_xor(p5,m);
        }
        if (lane == 0) {
            float* dst = accum + (long)gf * 32;
            atomAddF(dst+16,p0); atomAddF(dst+17,p1); atomAddF(dst+18,p2);
            atomAddF(dst+19,p3); atomAddF(dst+20,p4); atomAddF(dst+21,p5);
            atomAddF(dst+22,e0); atomAddF(dst+23,e1); atomAddF(dst+24,e2);
        }
    } else {
        float* dst = accum + (long)g_l * 32;
        atomAddF(dst+16,p0); atomAddF(dst+17,p1); atomAddF(dst+18,p2);
        atomAddF(dst+19,p3); atomAddF(dst+20,p4); atomAddF(dst+21,p5);
        atomAddF(dst+22,e0); atomAddF(dst+23,e1); atomAddF(dst+24,e2);
    }
}

// ---- Pass D (merged): weighted, channel-contracted segment sums of
// x11 (e0), x10 (e1), x01 (e1). One wave = 64 nodes = 4 tiles of 16.
// 15 float4 wave-bursts per tile, 2-deep register double-buffer, no asm.
#define TILE_BODY(T, VC, VN) do {                                              \
    const long tb = base + (T) * 16;                                           \
    _Pragma("unroll") for (int u = 0; u < 9; ++u) {                            \
        int fi = 4 * (lane + 64 * u);                                          \
        *reinterpret_cast<float4*>(&LD11[(fi/144)*148 + (fi%144)]) = VC[u];    \
    }                                                                          \
    _Pragma("unroll") for (int u = 0; u < 3; ++u) {                            \
        int fi = 4 * (lane + 64 * u);                                          \
        int nn = fi / 48, kk = fi % 48;                                        \
        *reinterpret_cast<float4*>(&LDA[nn*50 + kk]) = VC[9 + u];              \
        *reinterpret_cast<float4*>(&LDB[nn*50 + kk]) = VC[12 + u];             \
    }                                                                          \
    if ((T) < 3) {                                                             \
        const float4* s11 = reinterpret_cast<const float4*>(x11 + (tb+16)*144);\
        const float4* sA  = reinterpret_cast<const float4*>(x10 + (tb+16)*48); \
        const float4* sB  = reinterpret_cast<const float4*>(x01 + (tb+16)*48); \
        _Pragma("unroll") for (int u = 0; u < 9; ++u) VN[u] = s11[lane + 64*u];\
        _Pragma("unroll") for (int u = 0; u < 3; ++u) {                        \
            VN[9 + u]  = sA[lane + 64*u];                                      \
            VN[12 + u] = sB[lane + 64*u];                                      \
        }                                                                      \
    }                                                                          \
    float y0 = 0.f, y1 = 0.f, y2 = 0.f, yA = 0.f, yB = 0.f;                    \
    _Pragma("unroll") for (int c = 0; c < 16; ++c) {                           \
        y0 = fmaf(wv11[c], LD11[n0*148 + c*9 + d0], y0);                       \
        y1 = fmaf(wv11[c], LD11[n1*148 + c*9 + d1], y1);                       \
        yA = fmaf(wvA[c],  src0[na0*50 + c*3 + da0], yA);                      \
    }                                                                          \
    if (lane < 16) {                                                           \
        _Pragma("unroll") for (int c = 0; c < 16; ++c)                         \
            y2 = fmaf(wv11[c], LD11[n2*148 + c*9 + d2], y2);                   \
    }                                                                          \
    if (lane < 32) {                                                           \
        _Pragma("unroll") for (int c = 0; c < 16; ++c)                         \
            yB = fmaf(wvB[c], LDB[na1*50 + c*3 + da1], yB);                    \
    }                                                                          \
    float e00 = __shfl(er0, (T)*16 + n0);                                      \
    float e01 = __shfl(er0, (T)*16 + n1);                                      \
    float e02 = __shfl(er0, (T)*16 + (n2 & 15));                               \
    float e1a = __shfl(er1, (T)*16 + na0);                                     \
    float e1b = __shfl(er1, (T)*16 + na1);                                     \
    int gf = gid[tb], gl2 = gid[tb + 15];                                      \
    if (gf == gl2) {                                                           \
        if (gf != cur) { flushW(cur); cur = gf; }                              \
        a110 = fmaf(e00, y0, a110);                                            \
        a111 = fmaf(e01, y1, a111);                                            \
        if (lane < 16) a112 = fmaf(e02, y2, a112);                             \
        aA = fmaf(e1a, yA, aA);                                                \
        if (lane < 32) aB = fmaf(e1b, yB, aB);                                 \
    } else {                                                                   \
        flushW(cur);                                                           \
        atomAddF(accum + (long)gid[tb+n0]*32 + 6 + d0, e00 * y0);              \
        atomAddF(accum + (long)gid[tb+n1]*32 + 6 + d1, e01 * y1);              \
        if (lane < 16) atomAddF(accum + (long)gid[tb+n2]*32 + 6 + d2, e02*y2); \
        atomAddF(accum + (long)gid[tb+na0]*32 + (isB0?3:0) + da0, e1a * yA);   \
        if (lane < 32) atomAddF(accum + (long)gid[tb+na1]*32 + 3 + da1, e1b*yB);\
        cur = gl2;                                                             \
    }                                                                          \
} while (0)

__global__ __launch_bounds__(128) void k_wsum(const float* __restrict__ x10,
        const float* __restrict__ x01, const float* __restrict__ x11,
        const float* __restrict__ ebp, const int* __restrict__ gid,
        const float* __restrict__ w10, const float* __restrict__ w01,
        const float* __restrict__ w11, float* __restrict__ accum, int N)
{
    __shared__ float LD11s[2][16 * 148];
    __shared__ float LDAs[2][16 * 50];
    __shared__ float LDBs[2][16 * 50];
    __shared__ float FLs[2][240];
    const int wid = threadIdx.x >> 6;
    const int lane = threadIdx.x & 63;
    const int wgl = (blockIdx.x * blockDim.x + threadIdx.x) >> 6;
    const long base = (long)wgl * 64;
    float* LD11 = LD11s[wid];
    float* LDA  = LDAs[wid];
    float* LDB  = LDBs[wid];
    float* F    = FLs[wid];

    // roles
    const int n0 = lane / 9,          d0 = lane % 9;
    const int n1 = (lane + 64) / 9,   d1 = (lane + 64) % 9;
    const int n2 = (lane + 128) / 9,  d2 = (lane + 128) % 9;   // used lane<16
    const bool isB0 = (lane >= 48);
    const int j0 = isB0 ? (lane - 48) : lane;
    const int na0 = j0 / 3, da0 = j0 % 3;
    const int j1 = 16 + lane;                                   // used lane<32
    const int na1 = (j1 / 3) & 15, da1 = j1 % 3;
    float* src0 = isB0 ? LDB : LDA;

    float wv11[16], wvA[16], wvB[16];
    #pragma unroll
    for (int c = 0; c < 16; ++c) {
        wv11[c] = w11[c];
        wvB[c]  = w01[c];
        wvA[c]  = isB0 ? w01[c] : w10[c];
    }

    float er0 = ebp[base + lane];
    float er1 = ebp[(long)N + base + lane];

    float a110 = 0.f, a111 = 0.f, a112 = 0.f, aA = 0.f, aB = 0.f;
    int cur = gid[base];

    auto flushW = [&](int g) {
        F[lane] = a110;
        F[64 + lane] = a111;
        if (lane < 16) F[128 + lane] = a112;
        F[144 + lane] = aA;
        if (lane < 32) F[208 + lane] = aB;
        if (lane < 9) {
            float s = 0.f;
            #pragma unroll
            for (int m = 0; m < 16; ++m) s += F[m * 9 + lane];
            atomAddF(accum + (long)g * 32 + 6 + lane, s);
        } else if (lane < 12) {
            int d = lane - 9;
            float s = 0.f;
            #pragma unroll
            for (int m = 0; m < 16; ++m) s += F[144 + m * 3 + d];
            atomAddF(accum + (long)g * 32 + d, s);
        } else if (lane < 15) {
            int d = lane - 12;
            float s = 0.f;
            #pragma unroll
            for (int m = 0; m < 16; ++m) s += F[192 + m * 3 + d];
            atomAddF(accum + (long)g * 32 + 3 + d, s);
        }
        a110 = a111 = a112 = aA = aB = 0.f;
    };

    float4 va[15], vb[15];
    {
        const float4* s11 = reinterpret_cast<const float4*>(x11 + base * 144);
        const float4* sA  = reinterpret_cast<const float4*>(x10 + base * 48);
        const float4* sB  = reinterpret_cast<const float4*>(x01 + base * 48);
        #pragma unroll
        for (int u = 0; u < 9; ++u) va[u] = s11[lane + 64 * u];
        #pragma unroll
        for (int u = 0; u < 3; ++u) { va[9 + u] = sA[lane + 64 * u]; va[12 + u] = sB[lane + 64 * u]; }
    }
    TILE_BODY(0, va, vb);
    TILE_BODY(1, vb, va);
    TILE_BODY(2, va, vb);
    TILE_BODY(3, vb, va);
    flushW(cur);
}

// --------------------------- Pass E: per-graph epilogue -----------------------
#define JROT(p, q) do { \
    float apq_ = S[p][q]; \
    if (fabsf(apq_) > 1e-20f) { \
        float app_ = S[p][p], aqq_ = S[q][q]; \
        float tau_ = (aqq_ - app_) / (2.0f * apq_); \
        float tt_ = copysignf(1.0f, tau_) / (fabsf(tau_) + sqrtf(1.0f + tau_ * tau_)); \
        float cc_ = 1.0f / sqrtf(1.0f + tt_ * tt_); \
        float ssn_ = tt_ * cc_; \
        _Pragma("unroll") for (int kk = 0; kk < 3; ++kk) { \
            float skp = S[kk][p], skq = S[kk][q]; \
            S[kk][p] = cc_ * skp - ssn_ * skq; S[kk][q] = ssn_ * skp + cc_ * skq; } \
        _Pragma("unroll") for (int kk = 0; kk < 3; ++kk) { \
            float spk = S[p][kk], sqk = S[q][kk]; \
            S[p][kk] = cc_ * spk - ssn_ * sqk; S[q][kk] = ssn_ * spk + cc_ * sqk; } \
        _Pragma("unroll") for (int kk = 0; kk < 3; ++kk) { \
            float vkp = V[kk][p], vkq = V[kk][q]; \
            V[kk][p] = cc_ * vkp - ssn_ * vkq; V[kk][q] = ssn_ * vkp + cc_ * vkq; } \
    } \
} while (0)

__global__ void k_final(const float* __restrict__ accum, float* __restrict__ out)
{
    int g = blockIdx.x * blockDim.x + threadIdx.x;
    if (g >= GG) return;
    const float* A_ = accum + (long)g * 32;
    float i0 = 1.f / A_[22], i1 = 1.f / A_[23], i2 = 1.f / A_[24];

    float o10[3], o01[3], o11[9];
    #pragma unroll
    for (int d = 0; d < 3; ++d) { o10[d] = A_[d] * i1; o01[d] = A_[3 + d] * i1; }
    #pragma unroll
    for (int d = 0; d < 9; ++d) o11[d] = A_[6 + d] * i0;

    float m1v[3], m2v[3];
    #pragma unroll
    for (int d = 0; d < 3; ++d) { m1v[d] = A_[16 + d] * i2; m2v[d] = A_[19 + d] * i2; }

    int sig[3]; sig[0] = 2; sig[1] = 0; sig[2] = 1;   // Q_MAT permutation
    float rv[9];
    #pragma unroll
    for (int a = 0; a < 3; ++a)
        #pragma unroll
        for (int b = 0; b < 3; ++b)
            rv[a * 3 + b] = o11[sig[a] * 3 + sig[b]];
    float ta[3], tb[3];
    #pragma unroll
    for (int a = 0; a < 3; ++a) { ta[a] = o10[sig[a]]; tb[a] = o01[sig[a]]; }

    float nn = 0.f;
    #pragma unroll
    for (int k = 0; k < 9; ++k) nn += rv[k] * rv[k];
    float invn = 1.f / fmaxf(sqrtf(nn), 1e-5f);
    float M[3][3];
    #pragma unroll
    for (int a = 0; a < 3; ++a)
        #pragma unroll
        for (int b = 0; b < 3; ++b)
            M[a][b] = rv[b * 3 + a] * invn;

    float S[3][3], V[3][3];
    #pragma unroll
    for (int a = 0; a < 3; ++a)
        #pragma unroll
        for (int b = 0; b < 3; ++b) {
            float acc = 0.f;
            #pragma unroll
            for (int k = 0; k < 3; ++k) acc += M[k][a] * M[k][b];
            S[a][b] = acc;
            V[a][b] = (a == b) ? 1.f : 0.f;
        }
    for (int sw = 0; sw < 12; ++sw) { JROT(0, 1); JROT(0, 2); JROT(1, 2); }

    float l0 = S[0][0], l1 = S[1][1], l2 = S[2][2];
    float e0x = V[0][0], e0y = V[1][0], e0z = V[2][0];
    float e1x = V[0][1], e1y = V[1][1], e1z = V[2][1];
    float e2x = V[0][2], e2y = V[1][2], e2z = V[2][2];
    float tfl;
    if (l0 < l1) { tfl=l0;l0=l1;l1=tfl; tfl=e0x;e0x=e1x;e1x=tfl; tfl=e0y;e0y=e1y;e1y=tfl; tfl=e0z;e0z=e1z;e1z=tfl; }
    if (l0 < l2) { tfl=l0;l0=l2;l2=tfl; tfl=e0x;e0x=e2x;e2x=tfl; tfl=e0y;e0y=e2y;e2y=tfl; tfl=e0z;e0z=e2z;e2z=tfl; }
    if (l1 < l2) { tfl=l1;l1=l2;l2=tfl; tfl=e1x;e1x=e2x;e2x=tfl; tfl=e1y;e1y=e2y;e2y=tfl; tfl=e1z;e1z=e2z;e2z=tfl; }

    float c2x = e0y * e1z - e0z * e1y;
    float c2y = e0z * e1x - e0x * e1z;
    float c2z = e0x * e1y - e0y * e1x;
    float cn = rsqrtf(fmaxf(c2x * c2x + c2y * c2y + c2z * c2z, 1e-30f));
    c2x *= cn; c2y *= cn; c2z *= cn;

    float u0x = M[0][0] * e0x + M[0][1] * e0y + M[0][2] * e0z;
    float u0y = M[1][0] * e0x + M[1][1] * e0y + M[1][2] * e0z;
    float u0z = M[2][0] * e0x + M[2][1] * e0y + M[2][2] * e0z;
    float un = rsqrtf(fmaxf(u0x * u0x + u0y * u0y + u0z * u0z, 1e-30f));
    u0x *= un; u0y *= un; u0z *= un;
    float u1x = M[0][0] * e1x + M[0][1] * e1y + M[0][2] * e1z;
    float u1y = M[1][0] * e1x + M[1][1] * e1y + M[1][2] * e1z;
    float u1z = M[2][0] * e1x + M[2][1] * e1y + M[2][2] * e1z;
    float dp = u0x * u1x + u0y * u1y + u0z * u1z;
    u1x -= dp * u0x; u1y -= dp * u0y; u1z -= dp * u0z;
    un = rsqrtf(fmaxf(u1x * u1x + u1y * u1y + u1z * u1z, 1e-30f));
    u1x *= un; u1y *= un; u1z *= un;
    float u2x = u0y * u1z - u0z * u1y;
    float u2y = u0z * u1x - u0x * u1z;
    float u2z = u0x * u1y - u0y * u1x;

    float R[3][3];
    R[0][0] = u0x * e0x + u1x * e1x + u2x * c2x;
    R[0][1] = u0x * e0y + u1x * e1y + u2x * c2y;
    R[0][2] = u0x * e0z + u1x * e1z + u2x * c2z;
    R[1][0] = u0y * e0x + u1y * e1x + u2y * c2x;
    R[1][1] = u0y * e0y + u1y * e1y + u2y * c2y;
    R[1][2] = u0y * e0z + u1y * e1z + u2y * c2z;
    R[2][0] = u0z * e0x + u1z * e1x + u2z * c2x;
    R[2][1] = u0z * e0y + u1z * e1y + u2z * c2y;
    R[2][2] = u0z * e0z + u1z * e1z + u2z * c2z;

    float tv[3];
    #pragma unroll
    for (int a = 0; a < 3; ++a) {
        float acc = m2v[a] + tb[a];
        #pragma unroll
        for (int b = 0; b < 3; ++b) acc -= R[a][b] * (m1v[b] + ta[b]);
        tv[a] = acc;
    }

    #pragma unroll
    for (int k = 0; k < 9; ++k) out[(long)g * 9 + k] = R[k / 3][k % 3];
    #pragma unroll
    for (int a = 0; a < 3; ++a) out[(long)GG * 9 + (long)g * 3 + a] = tv[a];
    #pragma unroll
    for (int k = 0; k < 9; ++k) out[(long)GG * 12 + (long)g * 9 + k] = rv[k];
}

extern "C" void kernel_launch(void* const* d_in, const int* in_sizes, int n_in,
                              void* d_out, int out_size, void* d_ws, size_t ws_size,
                              hipStream_t stream)
{
    const float* x00   = (const float*)d_in[0];
    const float* x10   = (const float*)d_in[1];
    const float* x01   = (const float*)d_in[2];
    const float* x11   = (const float*)d_in[3];
    const float* pos   = (const float*)d_in[4];
    const int*   gid   = (const int*)d_in[5];
    const float* gamma = (const float*)d_in[7];
    const float* beta  = (const float*)d_in[8];
    const float* lin_w = (const float*)d_in[9];
    const float* lin_b = (const float*)d_in[10];
    const float* w10   = (const float*)d_in[11];
    const float* w01   = (const float*)d_in[12];
    const float* w11   = (const float*)d_in[13];
    float* out = (float*)d_out;

    const int N = in_sizes[0] / NF;   // 262144

    // workspace layout (floats)
    float* ws = (float*)d_ws;
    float* gsum  = ws;                       // GG*64
    float* gsq   = gsum + GG * 64;           // GG*64
    float* gcnt  = gsq + GG * 64;            // GG
    float* accum = gcnt + GG;                // GG*32
    float* Aeff  = accum + GG * 32;          // GG*192
    float* Beff  = Aeff + GG * 192;          // GG*3
    float* ebp   = Beff + GG * 3;            // 3*N (planar)

    size_t zeroBytes = (size_t)(GG * 64 * 2 + GG + GG * 32) * sizeof(float);
    hipMemsetAsync(d_ws, 0, zeroBytes, stream);

    int blocksA = (N / 64) / 4;               // 1024
    int blocksL = (N / 64) / 2;               // 2048
    int blocksW = (N / 64) / 2;               // 2048 (2 waves/block, 64 nodes/wave)

    k_stats <<<blocksA, 256, 0, stream>>>(x00, gid, gsum, gsq, gcnt, N);
    k_prep  <<<GG, 64, 0, stream>>>(gsum, gsq, gcnt, gamma, beta, lin_w, lin_b, Aeff, Beff);
    k_logits<<<blocksL, 128, 0, stream>>>(x00, gid, pos, Aeff, Beff, ebp, accum, N);
    k_wsum  <<<blocksW, 128, 0, stream>>>(x10, x01, x11, ebp, gid, w10, w01, w11, accum, N);
    k_final <<<(GG + 63) / 64, 64, 0, stream>>>(accum, out);
}

// Round 7
// 180.030 us; speedup vs baseline: 1.3334x; 1.3334x over previous
//
#include <hip/hip_runtime.h>
#include <cstdint>
#include <cstddef>

#define GG 512
#define NF 64
#define EPSF 1e-5f

__device__ __forceinline__ void atomAddF(float* p, float v) {
    unsafeAtomicAdd(p, v);   // hardware global_atomic_add_f32
}

// ---------------- Pass A: per-graph sum / sumsq / count of x00 ----------------
__global__ __launch_bounds__(256) void k_stats(const float* __restrict__ x00, const int* __restrict__ gid,
                        float* __restrict__ gsum, float* __restrict__ gsq,
                        float* __restrict__ gcnt, int N)
{
    int w = (blockIdx.x * blockDim.x + threadIdx.x) >> 6;
    int lane = threadIdx.x & 63;
    long base = (long)w * 64;
    int gf = gid[base];
    int gl = gid[base + 63];
    if (gf == gl) {
        const float4* p = reinterpret_cast<const float4*>(x00 + base * NF) + lane;
        float s0=0,s1=0,s2=0,s3=0,q0=0,q1=0,q2=0,q3=0;
        #pragma unroll
        for (int k = 0; k < 16; ++k) {
            float4 v = p[k * 64];
            s0+=v.x; s1+=v.y; s2+=v.z; s3+=v.w;
            q0=fmaf(v.x,v.x,q0); q1=fmaf(v.y,v.y,q1); q2=fmaf(v.z,v.z,q2); q3=fmaf(v.w,v.w,q3);
        }
        #pragma unroll
        for (int m = 16; m < 64; m <<= 1) {
            s0+=__shfl_xor(s0,m); s1+=__shfl_xor(s1,m); s2+=__shfl_xor(s2,m); s3+=__shfl_xor(s3,m);
            q0+=__shfl_xor(q0,m); q1+=__shfl_xor(q1,m); q2+=__shfl_xor(q2,m); q3+=__shfl_xor(q3,m);
        }
        if (lane < 16) {
            float* ds = gsum + gf * NF + lane * 4;
            float* dq = gsq  + gf * NF + lane * 4;
            atomAddF(ds+0,s0); atomAddF(ds+1,s1); atomAddF(ds+2,s2); atomAddF(ds+3,s3);
            atomAddF(dq+0,q0); atomAddF(dq+1,q1); atomAddF(dq+2,q2); atomAddF(dq+3,q3);
        }
        if (lane == 0) atomAddF(&gcnt[gf], 64.0f);
    } else {
        int myg = gid[base + lane];
        int cur = gf;
        float s = 0.f, q = 0.f, cnt = 0.f;
        for (int k = 0; k < 64; ++k) {
            int g = __shfl(myg, k);
            if (g != cur) {
                atomAddF(&gsum[cur * NF + lane], s);
                atomAddF(&gsq [cur * NF + lane], q);
                if (lane == 0) atomAddF(&gcnt[cur], cnt);
                s = q = cnt = 0.f; cur = g;
            }
            float v = x00[(base + k) * NF + lane];
            s += v; q = fmaf(v, v, q); cnt += 1.f;
        }
        atomAddF(&gsum[cur * NF + lane], s);
        atomAddF(&gsq [cur * NF + lane], q);
        if (lane == 0) atomAddF(&gcnt[cur], cnt);
    }
}

// ------------- Per-graph effective affine weights for logits ------------------
__global__ void k_prep(const float* __restrict__ gsum, const float* __restrict__ gsq,
                       const float* __restrict__ gcnt,
                       const float* __restrict__ gamma, const float* __restrict__ beta,
                       const float* __restrict__ lin_w, const float* __restrict__ lin_b,
                       float* __restrict__ Aeff, float* __restrict__ Beff)
{
    int g = blockIdx.x;
    int c = threadIdx.x;           // 64 threads = 1 wave
    float cnt = fmaxf(gcnt[g], 1.f);
    float mean = gsum[g * NF + c] / cnt;
    float var  = gsq [g * NF + c] / cnt - mean * mean;
    float rs = rsqrtf(var + EPSF);
    float ga = gamma[c], be = beta[c];
    #pragma unroll
    for (int j = 0; j < 3; ++j) {
        float wv = lin_w[j * NF + c];
        Aeff[((long)g * 3 + j) * NF + c] = rs * ga * wv;
        float term = (be - mean * rs * ga) * wv;
        #pragma unroll
        for (int m = 32; m; m >>= 1) term += __shfl_xor(term, m);
        if (c == 0) Beff[g * 3 + j] = term + lin_b[j];
    }
}

// --------- Pass B: logits -> e (no max-shift), pos-weighted sums, e-sums ------
__global__ __launch_bounds__(128) void k_logits(const float* __restrict__ x00, const int* __restrict__ gid,
                         const float* __restrict__ pos,
                         const float* __restrict__ Aeff, const float* __restrict__ Beff,
                         float* __restrict__ ebp, float* __restrict__ accum, int N)
{
    __shared__ float T2[2][64 * 68];
    int wid = threadIdx.x >> 6;
    int lane = threadIdx.x & 63;
    long chunk = (long)blockIdx.x * 2 + wid;
    long base = chunk * 64;
    float* T = T2[wid];

    const float* src = x00 + base * NF;
    #pragma unroll
    for (int k = 0; k < 16; ++k) {
        int fl = k * 256 + lane * 4;
        float4 v = *reinterpret_cast<const float4*>(src + fl);
        int n = fl >> 6, c = fl & 63;
        *reinterpret_cast<float4*>(&T[n * 68 + c]) = v;
    }
    __syncthreads();

    int gf = gid[base], gl = gid[base + 63];
    float l0, l1, l2;
    int g_l;
    if (gf == gl) {
        g_l = gf;
        const float* ap = Aeff + (size_t)gf * 192;
        float a0a=0,a0b=0,a1a=0,a1b=0,a2a=0,a2b=0;
        #pragma unroll
        for (int t = 0; t < 16; ++t) {
            float4 xv = *reinterpret_cast<const float4*>(&T[lane * 68 + 4 * t]);
            float4 w0 = *reinterpret_cast<const float4*>(ap + 4 * t);
            float4 w1 = *reinterpret_cast<const float4*>(ap + 64 + 4 * t);
            float4 w2 = *reinterpret_cast<const float4*>(ap + 128 + 4 * t);
            a0a = fmaf(xv.x,w0.x,fmaf(xv.y,w0.y,a0a)); a0b = fmaf(xv.z,w0.z,fmaf(xv.w,w0.w,a0b));
            a1a = fmaf(xv.x,w1.x,fmaf(xv.y,w1.y,a1a)); a1b = fmaf(xv.z,w1.z,fmaf(xv.w,w1.w,a1b));
            a2a = fmaf(xv.x,w2.x,fmaf(xv.y,w2.y,a2a)); a2b = fmaf(xv.z,w2.z,fmaf(xv.w,w2.w,a2b));
        }
        l0 = a0a + a0b + Beff[gf*3+0];
        l1 = a1a + a1b + Beff[gf*3+1];
        l2 = a2a + a2b + Beff[gf*3+2];
    } else {
        g_l = gid[base + lane];
        const float* ap = Aeff + (size_t)g_l * 192;
        float a0=0,a1=0,a2=0;
        #pragma unroll
        for (int t = 0; t < 16; ++t) {
            float4 xv = *reinterpret_cast<const float4*>(&T[lane * 68 + 4 * t]);
            float4 w0 = *reinterpret_cast<const float4*>(ap + 4 * t);
            float4 w1 = *reinterpret_cast<const float4*>(ap + 64 + 4 * t);
            float4 w2 = *reinterpret_cast<const float4*>(ap + 128 + 4 * t);
            a0 = fmaf(xv.x,w0.x,fmaf(xv.y,w0.y,fmaf(xv.z,w0.z,fmaf(xv.w,w0.w,a0))));
            a1 = fmaf(xv.x,w1.x,fmaf(xv.y,w1.y,fmaf(xv.z,w1.z,fmaf(xv.w,w1.w,a1))));
            a2 = fmaf(xv.x,w2.x,fmaf(xv.y,w2.y,fmaf(xv.z,w2.z,fmaf(xv.w,w2.w,a2))));
        }
        l0 = a0 + Beff[g_l*3+0];
        l1 = a1 + Beff[g_l*3+1];
        l2 = a2 + Beff[g_l*3+2];
    }
    float e0 = expf(l0), e1 = expf(l1), e2 = expf(l2);
    long node = base + lane;
    ebp[node]            = e0;
    ebp[(long)N + node]  = e1;
    ebp[2L * N + node]   = e2;

    const float* pp = pos + node * 6;
    float2 v01 = *reinterpret_cast<const float2*>(pp);
    float2 v23 = *reinterpret_cast<const float2*>(pp + 2);
    float2 v45 = *reinterpret_cast<const float2*>(pp + 4);
    float p0 = v01.x*e2, p1 = v01.y*e2, p2 = v23.x*e2, p3 = v23.y*e2, p4 = v45.x*e2, p5 = v45.y*e2;
    if (gf == gl) {
        #pragma unroll
        for (int m = 1; m < 64; m <<= 1) {
            e0+=__shfl_xor(e0,m); e1+=__shfl_xor(e1,m); e2+=__shfl_xor(e2,m);
            p0+=__shfl_xor(p0,m); p1+=__shfl_xor(p1,m); p2+=__shfl_xor(p2,m);
            p3+=__shfl_xor(p3,m); p4+=__shfl_xor(p4,m); p5+=__shfl_xor(p5,m);
        }
        if (lane == 0) {
            float* dst = accum + (long)gf * 32;
            atomAddF(dst+16,p0); atomAddF(dst+17,p1); atomAddF(dst+18,p2);
            atomAddF(dst+19,p3); atomAddF(dst+20,p4); atomAddF(dst+21,p5);
            atomAddF(dst+22,e0); atomAddF(dst+23,e1); atomAddF(dst+24,e2);
        }
    } else {
        float* dst = accum + (long)g_l * 32;
        atomAddF(dst+16,p0); atomAddF(dst+17,p1); atomAddF(dst+18,p2);
        atomAddF(dst+19,p3); atomAddF(dst+20,p4); atomAddF(dst+21,p5);
        atomAddF(dst+22,e0); atomAddF(dst+23,e1); atomAddF(dst+24,e2);
    }
}

// ---- Pass D1: x11 contraction, block-per-tile (64 nodes / 256 threads) ------
// out[g][6+d] += sum_i e0[i] * sum_c w11[c] * x11[i,c,d]
__global__ __launch_bounds__(256) void k_w11(const float* __restrict__ x11,
        const float* __restrict__ ebp, const int* __restrict__ gid,
        const float* __restrict__ w11, float* __restrict__ accum, int N)
{
    __shared__ float LD[64 * 148];     // 37.9 KB tile, pad 148 (16B-aligned rows)
    __shared__ float EE[64];
    int tid = threadIdx.x;
    long tb = (long)blockIdx.x * 64;

    // coalesced burst: 9 float4 per thread
    const float4* src = reinterpret_cast<const float4*>(x11 + tb * 144);
    float4 v[9];
    #pragma unroll
    for (int u = 0; u < 9; ++u) v[u] = src[tid + 256 * u];
    if (tid < 64) EE[tid] = ebp[tb + tid];

    #pragma unroll
    for (int u = 0; u < 9; ++u) {
        int fi = 4 * (tid + 256 * u);
        int n = fi / 144, k = fi % 144;
        *reinterpret_cast<float4*>(&LD[n * 148 + k]) = v[u];
    }
    __syncthreads();

    float w[16];
    #pragma unroll
    for (int c = 0; c < 16; ++c) w[c] = w11[c];

    // 576 outputs: idx = tid, tid+256, tid+512(tid<64)
    float y[3]; int nn[3], dd[3];
    #pragma unroll
    for (int r = 0; r < 3; ++r) {
        int idx = tid + 256 * r;
        nn[r] = idx / 9; dd[r] = idx - 9 * nn[r];
        y[r] = 0.f;
        if (r < 2 || tid < 64) {
            float s = 0.f;
            #pragma unroll
            for (int c = 0; c < 16; ++c)
                s = fmaf(w[c], LD[nn[r] * 148 + c * 9 + dd[r]], s);
            y[r] = EE[nn[r]] * s;
        }
    }

    int gf = gid[tb], gl = gid[tb + 63];
    if (gf == gl) {
        __syncthreads();                 // all LD reads done; reuse LD as F
        float* F = LD;                   // F[d*64 + n]
        #pragma unroll
        for (int r = 0; r < 3; ++r)
            if (r < 2 || tid < 64) F[dd[r] * 64 + nn[r]] = y[r];
        __syncthreads();
        if (tid < 9) {
            float s = 0.f;
            #pragma unroll
            for (int n = 0; n < 64; ++n) s += F[tid * 64 + n];
            atomAddF(accum + (long)gf * 32 + 6 + tid, s);
        }
    } else {
        #pragma unroll
        for (int r = 0; r < 3; ++r)
            if (r < 2 || tid < 64)
                atomAddF(accum + (long)gid[tb + nn[r]] * 32 + 6 + dd[r], y[r]);
    }
}

// ---- Pass D2: x10 & x01 contraction, block-per-tile ---------------------------
// out[g][0..2] += sum e1*w10.x10 ; out[g][3..5] += sum e1*w01.x01
__global__ __launch_bounds__(256) void k_w1001(const float* __restrict__ x10,
        const float* __restrict__ x01, const float* __restrict__ ebp,
        const int* __restrict__ gid,
        const float* __restrict__ w10, const float* __restrict__ w01,
        float* __restrict__ accum, int N)
{
    __shared__ float LDa[64 * 52];     // 13.3 KB, pad 52
    __shared__ float LDb[64 * 52];
    __shared__ float EE[64];
    int tid = threadIdx.x;
    long tb = (long)blockIdx.x * 64;

    const float4* sa = reinterpret_cast<const float4*>(x10 + tb * 48);
    const float4* sb = reinterpret_cast<const float4*>(x01 + tb * 48);
    float4 va[3], vb[3];
    #pragma unroll
    for (int u = 0; u < 3; ++u) { va[u] = sa[tid + 256 * u]; vb[u] = sb[tid + 256 * u]; }
    if (tid < 64) EE[tid] = ebp[(long)N + tb + tid];

    #pragma unroll
    for (int u = 0; u < 3; ++u) {
        int fi = 4 * (tid + 256 * u);
        int n = fi / 48, k = fi % 48;
        *reinterpret_cast<float4*>(&LDa[n * 52 + k]) = va[u];
        *reinterpret_cast<float4*>(&LDb[n * 52 + k]) = vb[u];
    }
    __syncthreads();

    float wA[16], wB[16];
    #pragma unroll
    for (int c = 0; c < 16; ++c) { wA[c] = w10[c]; wB[c] = w01[c]; }

    // 384 outputs: idx = tid, and tid+256 for tid<128
    float y[2]; int nn[2], dd[2], ar[2];
    #pragma unroll
    for (int r = 0; r < 2; ++r) {
        int idx = tid + 256 * r;
        ar[r] = idx / 192;
        int j = idx - 192 * ar[r];
        nn[r] = j / 3; dd[r] = j - 3 * nn[r];
        y[r] = 0.f;
        if (r < 1 || tid < 128) {
            const float* Lx = ar[r] ? LDb : LDa;
            float s = 0.f;
            #pragma unroll
            for (int c = 0; c < 16; ++c) {
                float wc = ar[r] ? wB[c] : wA[c];
                s = fmaf(wc, Lx[nn[r] * 52 + c * 3 + dd[r]], s);
            }
            y[r] = EE[nn[r]] * s;
        }
    }

    int gf = gid[tb], gl = gid[tb + 63];
    if (gf == gl) {
        __syncthreads();
        float* F = LDa;                  // F[ar*192 + d*64 + n]
        #pragma unroll
        for (int r = 0; r < 2; ++r)
            if (r < 1 || tid < 128) F[ar[r] * 192 + dd[r] * 64 + nn[r]] = y[r];
        __syncthreads();
        if (tid < 6) {
            int a = tid / 3, d = tid - 3 * a;
            float s = 0.f;
            #pragma unroll
            for (int n = 0; n < 64; ++n) s += F[a * 192 + d * 64 + n];
            atomAddF(accum + (long)gf * 32 + a * 3 + d, s);
        }
    } else {
        #pragma unroll
        for (int r = 0; r < 2; ++r)
            if (r < 1 || tid < 128)
                atomAddF(accum + (long)gid[tb + nn[r]] * 32 + ar[r] * 3 + dd[r], y[r]);
    }
}

// --------------------------- Pass E: per-graph epilogue -----------------------
#define JROT(p, q) do { \
    float apq_ = S[p][q]; \
    if (fabsf(apq_) > 1e-20f) { \
        float app_ = S[p][p], aqq_ = S[q][q]; \
        float tau_ = (aqq_ - app_) / (2.0f * apq_); \
        float tt_ = copysignf(1.0f, tau_) / (fabsf(tau_) + sqrtf(1.0f + tau_ * tau_)); \
        float cc_ = 1.0f / sqrtf(1.0f + tt_ * tt_); \
        float ssn_ = tt_ * cc_; \
        _Pragma("unroll") for (int kk = 0; kk < 3; ++kk) { \
            float skp = S[kk][p], skq = S[kk][q]; \
            S[kk][p] = cc_ * skp - ssn_ * skq; S[kk][q] = ssn_ * skp + cc_ * skq; } \
        _Pragma("unroll") for (int kk = 0; kk < 3; ++kk) { \
            float spk = S[p][kk], sqk = S[q][kk]; \
            S[p][kk] = cc_ * spk - ssn_ * sqk; S[q][kk] = ssn_ * spk + cc_ * sqk; } \
        _Pragma("unroll") for (int kk = 0; kk < 3; ++kk) { \
            float vkp = V[kk][p], vkq = V[kk][q]; \
            V[kk][p] = cc_ * vkp - ssn_ * vkq; V[kk][q] = ssn_ * vkp + cc_ * vkq; } \
    } \
} while (0)

__global__ void k_final(const float* __restrict__ accum, float* __restrict__ out)
{
    int g = blockIdx.x * blockDim.x + threadIdx.x;
    if (g >= GG) return;
    const float* A_ = accum + (long)g * 32;
    float i0 = 1.f / A_[22], i1 = 1.f / A_[23], i2 = 1.f / A_[24];

    float o10[3], o01[3], o11[9];
    #pragma unroll
    for (int d = 0; d < 3; ++d) { o10[d] = A_[d] * i1; o01[d] = A_[3 + d] * i1; }
    #pragma unroll
    for (int d = 0; d < 9; ++d) o11[d] = A_[6 + d] * i0;

    float m1v[3], m2v[3];
    #pragma unroll
    for (int d = 0; d < 3; ++d) { m1v[d] = A_[16 + d] * i2; m2v[d] = A_[19 + d] * i2; }

    int sig[3]; sig[0] = 2; sig[1] = 0; sig[2] = 1;   // Q_MAT permutation
    float rv[9];
    #pragma unroll
    for (int a = 0; a < 3; ++a)
        #pragma unroll
        for (int b = 0; b < 3; ++b)
            rv[a * 3 + b] = o11[sig[a] * 3 + sig[b]];
    float ta[3], tb[3];
    #pragma unroll
    for (int a = 0; a < 3; ++a) { ta[a] = o10[sig[a]]; tb[a] = o01[sig[a]]; }

    float nn = 0.f;
    #pragma unroll
    for (int k = 0; k < 9; ++k) nn += rv[k] * rv[k];
    float invn = 1.f / fmaxf(sqrtf(nn), 1e-5f);
    float M[3][3];
    #pragma unroll
    for (int a = 0; a < 3; ++a)
        #pragma unroll
        for (int b = 0; b < 3; ++b)
            M[a][b] = rv[b * 3 + a] * invn;

    float S[3][3], V[3][3];
    #pragma unroll
    for (int a = 0; a < 3; ++a)
        #pragma unroll
        for (int b = 0; b < 3; ++b) {
            float acc = 0.f;
            #pragma unroll
            for (int k = 0; k < 3; ++k) acc += M[k][a] * M[k][b];
            S[a][b] = acc;
            V[a][b] = (a == b) ? 1.f : 0.f;
        }
    for (int sw = 0; sw < 12; ++sw) { JROT(0, 1); JROT(0, 2); JROT(1, 2); }

    float l0 = S[0][0], l1 = S[1][1], l2 = S[2][2];
    float e0x = V[0][0], e0y = V[1][0], e0z = V[2][0];
    float e1x = V[0][1], e1y = V[1][1], e1z = V[2][1];
    float e2x = V[0][2], e2y = V[1][2], e2z = V[2][2];
    float tfl;
    if (l0 < l1) { tfl=l0;l0=l1;l1=tfl; tfl=e0x;e0x=e1x;e1x=tfl; tfl=e0y;e0y=e1y;e1y=tfl; tfl=e0z;e0z=e1z;e1z=tfl; }
    if (l0 < l2) { tfl=l0;l0=l2;l2=tfl; tfl=e0x;e0x=e2x;e2x=tfl; tfl=e0y;e0y=e2y;e2y=tfl; tfl=e0z;e0z=e2z;e2z=tfl; }
    if (l1 < l2) { tfl=l1;l1=l2;l2=tfl; tfl=e1x;e1x=e2x;e2x=tfl; tfl=e1y;e1y=e2y;e2y=tfl; tfl=e1z;e1z=e2z;e2z=tfl; }

    float c2x = e0y * e1z - e0z * e1y;
    float c2y = e0z * e1x - e0x * e1z;
    float c2z = e0x * e1y - e0y * e1x;
    float cn = rsqrtf(fmaxf(c2x * c2x + c2y * c2y + c2z * c2z, 1e-30f));
    c2x *= cn; c2y *= cn; c2z *= cn;

    float u0x = M[0][0] * e0x + M[0][1] * e0y + M[0][2] * e0z;
    float u0y = M[1][0] * e0x + M[1][1] * e0y + M[1][2] * e0z;
    float u0z = M[2][0] * e0x + M[2][1] * e0y + M[2][2] * e0z;
    float un = rsqrtf(fmaxf(u0x * u0x + u0y * u0y + u0z * u0z, 1e-30f));
    u0x *= un; u0y *= un; u0z *= un;
    float u1x = M[0][0] * e1x + M[0][1] * e1y + M[0][2] * e1z;
    float u1y = M[1][0] * e1x + M[1][1] * e1y + M[1][2] * e1z;
    float u1z = M[2][0] * e1x + M[2][1] * e1y + M[2][2] * e1z;
    float dp = u0x * u1x + u0y * u1y + u0z * u1z;
    u1x -= dp * u0x; u1y -= dp * u0y; u1z -= dp * u0z;
    un = rsqrtf(fmaxf(u1x * u1x + u1y * u1y + u1z * u1z, 1e-30f));
    u1x *= un; u1y *= un; u1z *= un;
    float u2x = u0y * u1z - u0z * u1y;
    float u2y = u0z * u1x - u0x * u1z;
    float u2z = u0x * u1y - u0y * u1x;

    float R[3][3];
    R[0][0] = u0x * e0x + u1x * e1x + u2x * c2x;
    R[0][1] = u0x * e0y + u1x * e1y + u2x * c2y;
    R[0][2] = u0x * e0z + u1x * e1z + u2x * c2z;
    R[1][0] = u0y * e0x + u1y * e1x + u2y * c2x;
    R[1][1] = u0y * e0y + u1y * e1y + u2y * c2y;
    R[1][2] = u0y * e0z + u1y * e1z + u2y * c2z;
    R[2][0] = u0z * e0x + u1z * e1x + u2z * c2x;
    R[2][1] = u0z * e0y + u1z * e1y + u2z * c2y;
    R[2][2] = u0z * e0z + u1z * e1z + u2z * c2z;

    float tv[3];
    #pragma unroll
    for (int a = 0; a < 3; ++a) {
        float acc = m2v[a] + tb[a];
        #pragma unroll
        for (int b = 0; b < 3; ++b) acc -= R[a][b] * (m1v[b] + ta[b]);
        tv[a] = acc;
    }

    #pragma unroll
    for (int k = 0; k < 9; ++k) out[(long)g * 9 + k] = R[k / 3][k % 3];
    #pragma unroll
    for (int a = 0; a < 3; ++a) out[(long)GG * 9 + (long)g * 3 + a] = tv[a];
    #pragma unroll
    for (int k = 0; k < 9; ++k) out[(long)GG * 12 + (long)g * 9 + k] = rv[k];
}

extern "C" void kernel_launch(void* const* d_in, const int* in_sizes, int n_in,
                              void* d_out, int out_size, void* d_ws, size_t ws_size,
                              hipStream_t stream)
{
    const float* x00   = (const float*)d_in[0];
    const float* x10   = (const float*)d_in[1];
    const float* x01   = (const float*)d_in[2];
    const float* x11   = (const float*)d_in[3];
    const float* pos   = (const float*)d_in[4];
    const int*   gid   = (const int*)d_in[5];
    const float* gamma = (const float*)d_in[7];
    const float* beta  = (const float*)d_in[8];
    const float* lin_w = (const float*)d_in[9];
    const float* lin_b = (const float*)d_in[10];
    const float* w10   = (const float*)d_in[11];
    const float* w01   = (const float*)d_in[12];
    const float* w11   = (const float*)d_in[13];
    float* out = (float*)d_out;

    const int N = in_sizes[0] / NF;   // 262144

    // workspace layout (floats)
    float* ws = (float*)d_ws;
    float* gsum  = ws;                       // GG*64
    float* gsq   = gsum + GG * 64;           // GG*64
    float* gcnt  = gsq + GG * 64;            // GG
    float* accum = gcnt + GG;                // GG*32
    float* Aeff  = accum + GG * 32;          // GG*192
    float* Beff  = Aeff + GG * 192;          // GG*3
    float* ebp   = Beff + GG * 3;            // 3*N (planar)

    size_t zeroBytes = (size_t)(GG * 64 * 2 + GG + GG * 32) * sizeof(float);
    hipMemsetAsync(d_ws, 0, zeroBytes, stream);

    int blocksA = (N / 64) / 4;               // 1024
    int blocksL = (N / 64) / 2;               // 2048
    int blocksT = N / 64;                     // 4096 (one 64-node tile per block)

    k_stats <<<blocksA, 256, 0, stream>>>(x00, gid, gsum, gsq, gcnt, N);
    k_prep  <<<GG, 64, 0, stream>>>(gsum, gsq, gcnt, gamma, beta, lin_w, lin_b, Aeff, Beff);
    k_logits<<<blocksL, 128, 0, stream>>>(x00, gid, pos, Aeff, Beff, ebp, accum, N);
    k_w11   <<<blocksT, 256, 0, stream>>>(x11, ebp, gid, w11, accum, N);
    k_w1001 <<<blocksT, 256, 0, stream>>>(x10, x01, ebp, gid, w10, w01, accum, N);
    k_final <<<(GG + 63) / 64, 64, 0, stream>>>(accum, out);
}